// Round 4
// baseline (2110.776 us; speedup 1.0000x reference)
//
#include <hip/hip_runtime.h>
#include <hip/hip_bf16.h>
#include <math.h>

#define SGRID 9216      // 96*96
#define NANCH 82944     // 9216*9
#define NSORT 131072    // pow2 >= worst-case candidate count (82944)
#define MAXOUT 2000

// ---------- helpers ----------
__device__ __forceinline__ bool iou_gt07(const float4 bi, const float4 bj) {
  float a1 = __fmul_rn(bi.z - bi.x, bi.w - bi.y);
  float a2 = __fmul_rn(bj.z - bj.x, bj.w - bj.y);
  float xx1 = fmaxf(bi.x, bj.x), yy1 = fmaxf(bi.y, bj.y);
  float xx2 = fminf(bi.z, bj.z), yy2 = fminf(bi.w, bj.w);
  float inter = __fmul_rn(fmaxf(xx2 - xx1, 0.f), fmaxf(yy2 - yy1, 0.f));
  float den = ((a1 + a2) - inter) + 1e-9f;
  return __fdiv_rn(inter, den) > 0.7f;
}

// ---------- init ----------
__global__ void k_init(unsigned long long* keys, unsigned int* ctrs) {
  int i = blockIdx.x * 256 + threadIdx.x;
  if (i < NSORT) keys[i] = 0ull;
  if (i < 8) ctrs[i] = 0u;
}

// ---------- conv 3x3 (256->256, SAME, relu) ----------
__global__ __launch_bounds__(256) void k_conv3(const float* __restrict__ x,
                                               const float* __restrict__ w,
                                               const float* __restrict__ bias,
                                               float* __restrict__ h) {
  __shared__ float xs[8][3][98];
  __shared__ float ws[128][72];
  const int y = blockIdx.x;
  const int oc0 = blockIdx.y * 128;
  const int t = threadIdx.x;
  const int og = t >> 4;
  const int xg = t & 15;
  float acc[8][6];
#pragma unroll
  for (int a = 0; a < 8; a++)
#pragma unroll
    for (int c = 0; c < 6; c++) acc[a][c] = 0.f;

  for (int ic0 = 0; ic0 < 256; ic0 += 8) {
    for (int idx = t; idx < 8 * 3 * 98; idx += 256) {
      int ic = idx / (3 * 98);
      int r = (idx / 98) % 3;
      int xp = idx % 98;
      int yy = y + r - 1, xxs = xp - 1;
      float v = 0.f;
      if (yy >= 0 && yy < 96 && xxs >= 0 && xxs < 96)
        v = x[(ic0 + ic) * SGRID + yy * 96 + xxs];
      xs[ic][r][xp] = v;
    }
    for (int q = t; q < 128 * 18; q += 256) {
      int oc = q / 18, j4 = q % 18;
      float4 v = *(const float4*)(w + (size_t)(oc0 + oc) * 2304 + ic0 * 9 + j4 * 4);
      *(float4*)(&ws[oc][j4 * 4]) = v;
    }
    __syncthreads();
#pragma unroll
    for (int ic = 0; ic < 8; ic++) {
#pragma unroll
      for (int r = 0; r < 3; r++) {
        float xr[8];
#pragma unroll
        for (int u = 0; u < 8; u++) xr[u] = xs[ic][r][xg * 6 + u];
#pragma unroll
        for (int a = 0; a < 8; a++) {
          float w0 = ws[og * 8 + a][ic * 9 + r * 3 + 0];
          float w1 = ws[og * 8 + a][ic * 9 + r * 3 + 1];
          float w2 = ws[og * 8 + a][ic * 9 + r * 3 + 2];
#pragma unroll
          for (int c = 0; c < 6; c++)
            acc[a][c] += xr[c] * w0 + xr[c + 1] * w1 + xr[c + 2] * w2;
        }
      }
    }
    __syncthreads();
  }
#pragma unroll
  for (int a = 0; a < 8; a++) {
    int oc = oc0 + og * 8 + a;
    float bb = bias[oc];
#pragma unroll
    for (int c = 0; c < 6; c++) {
      float v = acc[a][c] + bb;
      h[(size_t)oc * SGRID + y * 96 + xg * 6 + c] = v > 0.f ? v : 0.f;
    }
  }
}

// ---------- 1x1 heads (256 -> 36 + 18, relu) ----------
__global__ __launch_bounds__(256) void k_conv1x1(const float* __restrict__ h,
                                                 const float* __restrict__ bw, const float* __restrict__ bb,
                                                 const float* __restrict__ sw, const float* __restrict__ sb,
                                                 float* __restrict__ bbox, float* __restrict__ score) {
  __shared__ float wcat[54][256];
  const int t = threadIdx.x;
  const int p0 = blockIdx.x * 512;
  for (int idx = t; idx < 54 * 64; idx += 256) {
    int c = idx >> 6, k4 = idx & 63;
    const float* src = (c < 36) ? (bw + c * 256) : (sw + (c - 36) * 256);
    float4 v = *(const float4*)(src + k4 * 4);
    *(float4*)(&wcat[c][k4 * 4]) = v;
  }
  __syncthreads();
  const int pa = p0 + t, pb = p0 + 256 + t;
  float accA[54], accB[54];
#pragma unroll
  for (int c = 0; c < 54; c++) { accA[c] = 0.f; accB[c] = 0.f; }
  for (int k0 = 0; k0 < 256; k0 += 8) {
    float ha[8], hb[8];
#pragma unroll
    for (int u = 0; u < 8; u++) {
      ha[u] = h[(size_t)(k0 + u) * SGRID + pa];
      hb[u] = h[(size_t)(k0 + u) * SGRID + pb];
    }
#pragma unroll
    for (int c = 0; c < 54; c++) {
      float4 w0 = *(const float4*)(&wcat[c][k0]);
      float4 w1 = *(const float4*)(&wcat[c][k0 + 4]);
      accA[c] += ha[0] * w0.x + ha[1] * w0.y + ha[2] * w0.z + ha[3] * w0.w
               + ha[4] * w1.x + ha[5] * w1.y + ha[6] * w1.z + ha[7] * w1.w;
      accB[c] += hb[0] * w0.x + hb[1] * w0.y + hb[2] * w0.z + hb[3] * w0.w
               + hb[4] * w1.x + hb[5] * w1.y + hb[6] * w1.z + hb[7] * w1.w;
    }
  }
#pragma unroll
  for (int c = 0; c < 36; c++) {
    float va = accA[c] + bb[c], vb = accB[c] + bb[c];
    bbox[(size_t)c * SGRID + pa] = va > 0.f ? va : 0.f;
    bbox[(size_t)c * SGRID + pb] = vb > 0.f ? vb : 0.f;
  }
#pragma unroll
  for (int c = 36; c < 54; c++) {
    float va = accA[c] + sb[c - 36], vb = accB[c] + sb[c - 36];
    score[(size_t)(c - 36) * SGRID + pa] = va > 0.f ? va : 0.f;
    score[(size_t)(c - 36) * SGRID + pb] = vb > 0.f ? vb : 0.f;
  }
}

// ---------- decode + filter + candidate compaction ----------
__global__ void k_decode(const float* __restrict__ bbox, const float* __restrict__ score,
                         float4* __restrict__ boxes, unsigned long long* __restrict__ keys,
                         unsigned int* __restrict__ cnt) {
  int a = blockIdx.x * 256 + threadIdx.x;
  if (a >= NANCH) return;
  int i = a / 864;
  int rem = a - i * 864;
  int j = rem / 9;
  int k = rem - j * 9;
  const double areas[3] = {16384.0, 65536.0, 262144.0};
  int ai = k / 3, ri = k - ai * 3;
  double wr = (ri == 1) ? 2.0 : 1.0;
  double hr = (ri == 2) ? 2.0 : 1.0;
  double u = sqrt(areas[ai] / (wr * hr));
  double wd = wr * u, hd = hr * u;
  double cxd = (i + 0.5) * 16.0, cyd = (j + 0.5) * 16.0;
  float ax1 = (float)(cxd - wd * 0.5), ax2 = (float)(cxd + wd * 0.5);
  float ay1 = (float)(cyd - hd * 0.5), ay2 = (float)(cyd + hd * 0.5);
  float wa = ax2 - ax1, haa = ay2 - ay1;
  float cxa = (ax1 + ax2) * 0.5f, cya = (ay1 + ay2) * 0.5f;

  float4 br = ((const float4*)bbox)[a];
  float o0 = score[2 * (size_t)a];

  float cx = __fmul_rn(br.x, wa) + cxa;
  float cy = __fmul_rn(br.y, haa) + cya;
  float ww = __fmul_rn(expf(br.z), wa);
  float hh = __fmul_rn(expf(br.w), haa);
  float x1 = fminf(fmaxf(cx - __fmul_rn(ww, 0.5f), 0.f), 1536.f);
  float y1 = fminf(fmaxf(cy - __fmul_rn(hh, 0.5f), 0.f), 1536.f);
  float x2 = fminf(fmaxf(cx + __fmul_rn(ww, 0.5f), 0.f), 1536.f);
  float y2 = fminf(fmaxf(cy + __fmul_rn(hh, 0.5f), 0.f), 1536.f);
  boxes[a] = make_float4(x1, y1, x2, y2);
  float area = fabsf(__fmul_rn(x1 - x2, y1 - y2));
  if (o0 > 0.2f && area > 100.0f) {
    unsigned p = atomicAdd(cnt, 1u);
    keys[p] = ((unsigned long long)__float_as_uint(o0) << 32) |
              (unsigned long long)(0xFFFFFFFFu - (unsigned)a);
  }
}

// ---------- bitonic sort (descending), 131072 keys ----------
__global__ __launch_bounds__(1024) void k_sort_local(unsigned long long* keys) {
  __shared__ unsigned long long s[4096];
  const int base = blockIdx.x * 4096, t = threadIdx.x;
  for (int u = t; u < 4096; u += 1024) s[u] = keys[base + u];
  __syncthreads();
  for (int k = 2; k <= 4096; k <<= 1) {
    for (int j = k >> 1; j >= 1; j >>= 1) {
      for (int m = t; m < 2048; m += 1024) {
        int i = ((m & ~(j - 1)) << 1) | (m & (j - 1));
        int l = i | j;
        bool dir = (((base + i) & k) == 0);
        unsigned long long A = s[i], B = s[l];
        bool sw = dir ? (A < B) : (A > B);
        if (sw) { s[i] = B; s[l] = A; }
      }
      __syncthreads();
    }
  }
  for (int u = t; u < 4096; u += 1024) keys[base + u] = s[u];
}

__global__ void k_sort_global(unsigned long long* keys, int k, int j) {
  int m = blockIdx.x * 256 + threadIdx.x;
  int i = ((m & ~(j - 1)) << 1) | (m & (j - 1));
  int l = i | j;
  bool dir = ((i & k) == 0);
  unsigned long long A = keys[i], B = keys[l];
  bool sw = dir ? (A < B) : (A > B);
  if (sw) { keys[i] = B; keys[l] = A; }
}

__global__ __launch_bounds__(1024) void k_sort_localmerge(unsigned long long* keys, int k) {
  __shared__ unsigned long long s[4096];
  const int base = blockIdx.x * 4096, t = threadIdx.x;
  for (int u = t; u < 4096; u += 1024) s[u] = keys[base + u];
  __syncthreads();
  const bool dir = ((base & k) == 0);
  for (int j = 2048; j >= 1; j >>= 1) {
    for (int m = t; m < 2048; m += 1024) {
      int i = ((m & ~(j - 1)) << 1) | (m & (j - 1));
      int l = i | j;
      unsigned long long A = s[i], B = s[l];
      bool sw = dir ? (A < B) : (A > B);
      if (sw) { s[i] = B; s[l] = A; }
    }
    __syncthreads();
  }
  for (int u = t; u < 4096; u += 1024) keys[base + u] = s[u];
}

// ---------- exact greedy NMS over sorted candidates, chunked (single block) ----------
__global__ __launch_bounds__(256) void k_nms(const unsigned long long* __restrict__ keys,
                                             const float4* __restrict__ boxes,
                                             const unsigned int* __restrict__ cntp,
                                             unsigned int* __restrict__ acc,
                                             unsigned int* __restrict__ nap) {
  __shared__ float4 ab[MAXOUT];
  __shared__ float4 cb[64];
  __shared__ unsigned int cba[64];
  __shared__ unsigned long long selfm[64];
  __shared__ unsigned long long ssup;
  __shared__ unsigned int sna;
  const int t = threadIdx.x;
  const unsigned cnt = *cntp;
  if (t == 0) sna = 0u;
  __syncthreads();
  for (unsigned q0 = 0; q0 < cnt; q0 += 64) {
    unsigned nr = cnt - q0; if (nr > 64u) nr = 64u;
    if (t < 64) {
      if ((unsigned)t < nr) {
        unsigned a = 0xFFFFFFFFu - (unsigned)(keys[q0 + t] & 0xFFFFFFFFull);
        cba[t] = a;
        cb[t] = boxes[a];
      } else {
        cb[t] = make_float4(3e9f, 3e9f, 3e9f, 3e9f);
        cba[t] = 0u;
      }
    }
    if (t == 0) ssup = 0ull;
    __syncthreads();
    if (t < 64) {
      float4 bi = cb[t];
      unsigned long long bits = 0ull;
      for (int b = 0; b < 64; b++)
        if (iou_gt07(bi, cb[b])) bits |= (1ull << b);
      selfm[t] = bits;
    }
    const unsigned na0 = sna;
    unsigned long long mybits = 0ull;
    const int colg = (t & 3) * 16;
    for (unsigned u = (unsigned)(t >> 2); u < na0; u += 64u) {
      float4 au = ab[u];
#pragma unroll
      for (int b2 = 0; b2 < 16; b2++)
        if (iou_gt07(au, cb[colg + b2])) mybits |= (1ull << (colg + b2));
    }
    if (mybits) atomicOr(&ssup, mybits);
    __syncthreads();
    if (t == 0) {
      unsigned long long w = ~ssup;
      if (nr < 64u) w &= ((1ull << nr) - 1ull);
      unsigned na = sna;
      while (w && na < MAXOUT) {
        int b = __builtin_ctzll(w);
        ab[na] = cb[b];
        acc[na] = cba[b];
        na++;
        w &= ~selfm[b];
      }
      sna = na;
    }
    __syncthreads();
    if (sna >= MAXOUT) break;
  }
  if (t == 0) *nap = sna;
}

// ---------- write outputs (FLOAT32 — reference returns f32) ----------
__global__ void k_output(const float4* __restrict__ boxes, const float* __restrict__ score,
                         const unsigned int* __restrict__ acc, const unsigned int* __restrict__ nap,
                         float* __restrict__ out) {
  int tdx = blockIdx.x * 256 + threadIdx.x;
  if (tdx >= MAXOUT) return;
  unsigned na = *nap;
  float4 b = make_float4(0.f, 0.f, 0.f, 0.f);
  float o0 = 0.f, o1 = 0.f;
  if (tdx < (int)na) {
    unsigned a = acc[tdx];
    b = boxes[a];
    o0 = score[2 * (size_t)a];
    o1 = score[2 * (size_t)a + 1];
  }
  out[tdx * 4 + 0] = b.x;
  out[tdx * 4 + 1] = b.y;
  out[tdx * 4 + 2] = b.z;
  out[tdx * 4 + 3] = b.w;
  out[8000 + tdx * 2 + 0] = o0;
  out[8000 + tdx * 2 + 1] = o1;
}

// ---------- DIAGNOSTIC PROBE: only fires if a pipeline stage looks dead ----------
__global__ __launch_bounds__(256) void k_probe(const float* __restrict__ h,
                                               const float* __restrict__ score,
                                               const unsigned long long* __restrict__ keys,
                                               const unsigned int* __restrict__ ctrs,
                                               float* __restrict__ out) {
  __shared__ unsigned sf;
  const int t = threadIdx.x;
  if (t == 0) sf = 0u;
  __syncthreads();
  unsigned local = 0u;
  for (int i = t; i < 4096; i += 256)
    if (h[(size_t)i * 575] > 0.f) { local |= 1u; break; }       // bit0: conv3 live
  for (int i = t; i < 4096; i += 256)
    if (score[(size_t)i * 40] > 0.2f) { local |= 2u; break; }   // bit1: head live
  if (t == 0) {
    unsigned cnt = ctrs[0], na = ctrs[1];
    if (cnt > 0u)                local |= 4u;                    // bit2: filter fired
    if (cnt >= 4096u)            local |= 8u;                    // bit3: count plausible
    if ((keys[0] >> 32) != 0ull) local |= 16u;                   // bit4: sort head live
    if (na >= 1u)                local |= 32u;                   // bit5: NMS accepted
    if (na >= 2000u)             local |= 64u;                   // bit6: reached MAX_OUT (info only)
  }
  atomicOr(&sf, local);
  __syncthreads();
  // healthy = bits 0..5 all set; then leave k_output's value untouched
  if (t == 0 && (sf & 63u) != 63u) out[0] = 1e6f * (1.f + (float)sf);
}

extern "C" void kernel_launch(void* const* d_in, const int* in_sizes, int n_in,
                              void* d_out, int out_size, void* d_ws, size_t ws_size,
                              hipStream_t stream) {
  const float* x       = (const float*)d_in[0];
  const float* conv_w  = (const float*)d_in[1];
  const float* conv_b  = (const float*)d_in[2];
  const float* bbox_w  = (const float*)d_in[3];
  const float* bbox_b  = (const float*)d_in[4];
  const float* score_w = (const float*)d_in[5];
  const float* score_b = (const float*)d_in[6];

  char* ws = (char*)d_ws;
  size_t off = 0;
  auto alloc = [&](size_t bytes) {
    void* p = ws + off;
    off = (off + bytes + 255) & ~(size_t)255;
    return p;
  };
  float* h                 = (float*)alloc((size_t)256 * SGRID * 4);
  float* bbox              = (float*)alloc((size_t)36 * SGRID * 4);
  float* score             = (float*)alloc((size_t)18 * SGRID * 4);
  float4* boxes            = (float4*)alloc((size_t)NANCH * 16);
  unsigned long long* keys = (unsigned long long*)alloc((size_t)NSORT * 8);
  unsigned int* acc        = (unsigned int*)alloc((size_t)2048 * 4);
  unsigned int* ctrs       = (unsigned int*)alloc(64);
  unsigned int* cnt = ctrs + 0;
  unsigned int* nap = ctrs + 1;
  (void)in_sizes; (void)n_in; (void)out_size; (void)ws_size;

  k_init<<<NSORT / 256, 256, 0, stream>>>(keys, ctrs);
  k_conv3<<<dim3(96, 2), 256, 0, stream>>>(x, conv_w, conv_b, h);
  k_conv1x1<<<18, 256, 0, stream>>>(h, bbox_w, bbox_b, score_w, score_b, bbox, score);
  k_decode<<<NANCH / 256, 256, 0, stream>>>(bbox, score, boxes, keys, cnt);

  k_sort_local<<<NSORT / 4096, 1024, 0, stream>>>(keys);
  for (int k = 8192; k <= NSORT; k <<= 1) {
    for (int j = k >> 1; j >= 4096; j >>= 1)
      k_sort_global<<<NSORT / 512, 256, 0, stream>>>(keys, k, j);
    k_sort_localmerge<<<NSORT / 4096, 1024, 0, stream>>>(keys, k);
  }

  k_nms<<<1, 256, 0, stream>>>(keys, boxes, cnt, acc, nap);
  k_output<<<(MAXOUT + 255) / 256, 256, 0, stream>>>(boxes, score, acc, nap, (float*)d_out);
  k_probe<<<1, 256, 0, stream>>>(h, score, keys, ctrs, (float*)d_out);
}